// Round 13
// baseline (676.644 us; speedup 1.0000x reference)
//
#include <hip/hip_runtime.h>
#include <stdint.h>

// Problem constants (fixed by reference)
#define BB   4
#define SS   2048
#define DD   1024
#define EE   64
#define CAP  64
#define NTOK (BB*SS)                       // 8192 tokens
#define NROW (NTOK*EE)                     // 524,288 (b,s,e) rows
#define OUT1_ELEMS (BB*SS*EE*CAP)          // 33,554,432 per output tensor

// ============================================================================
// Round 13: SSE-4-LANE EINSUM REPLICA (single-variable change vs R12).
// Flip-count arithmetic: wrong einsum order -> logit noise ~1e-5 -> E[flips]
// ~100 over 16384 boundary pairs -> deterministic fail; wrong exp ulp ->
// E[flips]~0.4 -> coin flip. Sequential no-FMA einsum failed under THREE
// different exps (R6/R9/R12, combined p~0.1 if correct) => einsum order is
// the wrong piece. np.einsum optimize=False buffers the strided W column and
// runs float32 sum_of_products_contig_two: SSE1 4-lane accumulator, mul+add
// (no FMA), lane j sums k===j (mod 4) sequentially, horizontal via
// movehl+add_ss = (s0+s2)+(s1+s3). This round replicates that exactly.
// Held fixed (numpy replicas, R12): exact pow2 noise scale, order-indep max,
// npyv rational P5/Q2 exp, pairwise-8 denominator, rn division, exhaustive
// stable rank (ties -> lower token index). Plumbing proven by R8/R10
// sentinels (fp32 in/out, sizes OK, writer/decode verified).
// ============================================================================

// ---- numpy npyv fp32 exp replica (npy_simd_data.h constants) --------------
// Domain here: x = l - max in [-~13, 0] -> no overflow/underflow handling.
__device__ __forceinline__ float np_expf_npyv(float x) {
    float q = rintf(__fmul_rn(x, 1.442695040888963407e0f));
    float r = __fmaf_rn(q, -6.93145752e-1f, x);
    r = __fmaf_rn(q, -1.42860677e-6f, r);
    float num = 5.082762527590693718096e-04f;
    num = __fmaf_rn(num, r, 6.757896990527504603057e-03f);
    num = __fmaf_rn(num, r, 5.114512081637298353406e-02f);
    num = __fmaf_rn(num, r, 2.473615434895520810817e-01f);
    num = __fmaf_rn(num, r, 7.257664613233124478488e-01f);
    num = __fmaf_rn(num, r, 9.999999999980870924916e-01f);
    float den = 2.159509375685829852307e-02f;
    den = __fmaf_rn(den, r, -2.742335390411667452936e-01f);
    den = __fmaf_rn(den, r, 1.0f);
    float p = __fdiv_rn(num, den);
    return __fmul_rn(p, __int_as_float(((int)q + 127) << 23));
}

// ---------------------------------------------------------------------------
// Kernel 1: fp32 gates, mechanical-numpy arithmetic. 4 waves/block; one token
// per wave; lane = expert. Gate table (2 MiB fp32) at the start of the
// combine region (consumed by rank_kernel, then overwritten by writer).
// ---------------------------------------------------------------------------
__global__ __launch_bounds__(256) void gates_kernel(
        const float* __restrict__ X,       // [NTOK, DD]
        const float* __restrict__ W,       // [DD, EE]
        const float* __restrict__ Nz,      // [NTOK, EE]
        float* __restrict__ outb)
{
    float* G = outb + (size_t)OUT1_ELEMS;  // combine region head

    const int lane = threadIdx.x & 63;     // expert index
    const int wave = threadIdx.x >> 6;
    const int tok  = blockIdx.x * 4 + wave;

    // np.einsum contig_two SSE1 path: one 4-lane accumulator, mul THEN add
    // (no FMA); lane j accumulates products at k === j (mod 4) in ascending
    // order; horizontal reduction (movehl + add_ss) = (s0+s2) + (s1+s3).
    const float* xrow = X + (size_t)tok * DD;
    float s0 = 0.0f, s1 = 0.0f, s2 = 0.0f, s3 = 0.0f;
    for (int k = 0; k < DD; k += 4) {
        s0 = __fadd_rn(s0, __fmul_rn(xrow[k + 0], W[(size_t)(k + 0) * EE + lane]));
        s1 = __fadd_rn(s1, __fmul_rn(xrow[k + 1], W[(size_t)(k + 1) * EE + lane]));
        s2 = __fadd_rn(s2, __fmul_rn(xrow[k + 2], W[(size_t)(k + 2) * EE + lane]));
        s3 = __fadd_rn(s3, __fmul_rn(xrow[k + 3], W[(size_t)(k + 3) * EE + lane]));
    }
    float acc = __fadd_rn(__fadd_rn(s0, s2), __fadd_rn(s1, s3));

    // + noise * (1/64): pow2 scale exact; one rn add (np elementwise order)
    float nz = Nz[(size_t)tok * EE + lane];
    float l = __fadd_rn(acc, __fmul_rn(nz, 0.015625f));

    __shared__ float sl[4][64];
    __shared__ float sp[4][64];
    sl[wave][lane] = l;
    __syncthreads();

    // np.max over 64: order-independent for non-NaN
    float m = sl[wave][0];
    for (int i = 1; i < 64; ++i) m = fmaxf(m, sl[wave][i]);

    // np.exp(float32) npyv replica on rn(l - m)
    float p = np_expf_npyv(__fsub_rn(l, m));
    sp[wave][lane] = p;
    __syncthreads();

    // np.sum n=64 contiguous: pairwise_sum 8-accumulator path.
    float r0 = sp[wave][0], r1 = sp[wave][1], r2 = sp[wave][2], r3 = sp[wave][3];
    float r4 = sp[wave][4], r5 = sp[wave][5], r6 = sp[wave][6], r7 = sp[wave][7];
    for (int i = 8; i < 64; i += 8) {
        r0 = __fadd_rn(r0, sp[wave][i + 0]);
        r1 = __fadd_rn(r1, sp[wave][i + 1]);
        r2 = __fadd_rn(r2, sp[wave][i + 2]);
        r3 = __fadd_rn(r3, sp[wave][i + 3]);
        r4 = __fadd_rn(r4, sp[wave][i + 4]);
        r5 = __fadd_rn(r5, sp[wave][i + 5]);
        r6 = __fadd_rn(r6, sp[wave][i + 6]);
        r7 = __fadd_rn(r7, sp[wave][i + 7]);
    }
    float Z = __fadd_rn(__fadd_rn(__fadd_rn(r0, r1), __fadd_rn(r2, r3)),
                        __fadd_rn(__fadd_rn(r4, r5), __fadd_rn(r6, r7)));

    G[(size_t)tok * EE + lane] = __fdiv_rn(p, Z);
}

// ---------------------------------------------------------------------------
// Kernel 2: exhaustive rank per (b,e) on fp32 gate bits (positive floats:
// uint32 order == float order); ties -> LOWER token index (stable top_k).
// Header {rank+1:int, gate:fp32} at each mask row start.
// ---------------------------------------------------------------------------
__global__ __launch_bounds__(512) void rank_kernel(
        const float* __restrict__ outb_c,  // d_out (const view for G)
        float* __restrict__ outb)
{
    const float* G = outb_c + (size_t)OUT1_ELEMS;

    const int tid = threadIdx.x;           // 0..511
    const int be  = blockIdx.x;            // 0..255
    const int b   = be >> 6;
    const int e   = be & 63;

    __shared__ unsigned K[SS];             // 8 KB

    unsigned mine[4];
    int sown[4];
    float gv[4];
    #pragma unroll
    for (int j = 0; j < 4; ++j) {
        const int s = tid + 512 * j;       // covers 0..2047 exactly
        float g = G[((size_t)(b * SS + s)) * EE + e];
        unsigned bits = __float_as_uint(g);
        K[s]    = bits;
        mine[j] = bits;
        sown[j] = s;
        gv[j]   = g;
    }
    __syncthreads();

    int rank[4] = {0, 0, 0, 0};
    for (int i = 0; i < SS; ++i) {
        const unsigned ki = K[i];          // LDS broadcast, conflict-free
        #pragma unroll
        for (int j = 0; j < 4; ++j) {
            const int gt = (ki > mine[j]) ? 1 : 0;
            const int eq = ((ki == mine[j]) && (i < sown[j])) ? 1 : 0;
            rank[j] += gt + eq;
        }
    }

    #pragma unroll
    for (int j = 0; j < 4; ++j) {
        const size_t row = ((size_t)(b * SS + sown[j])) * EE + e;
        float* h = outb + row * CAP;       // mask row start
        ((int*)h)[0] = rank[j] + 1;        // 1..2048
        h[1]         = gv[j];              // gate value
    }
}

// ---------------------------------------------------------------------------
// Kernel 3: dense writer. 8 threads per (b,s,e) row; one wave owns a row
// (header load precedes the overwriting stores via data dependency).
// mask[c]=(c==rank); combine[c]=mask*gate; rank>=64 -> zero row.
// Fully coalesced 256 B row stores on both tensors.
// ---------------------------------------------------------------------------
__global__ __launch_bounds__(256) void writer_kernel(
        float* __restrict__ outb)
{
    const unsigned g = blockIdx.x * 256u + threadIdx.x;  // < 4,194,304
    const size_t row = g >> 3;             // (b,s,e) row, < NROW
    const int    c8  = g & 7;              // group of 8 capacity slots
    const int    c0  = c8 * 8;

    float* mrow = outb + row * CAP;
    const int   stored = ((const int*)mrow)[0];
    const float gate   = mrow[1];
    const int   rank   = stored - 1;

    float4 m0, m1, cc0, cc1;
    m0.x = (c0+0==rank)?1.f:0.f;  m0.y = (c0+1==rank)?1.f:0.f;
    m0.z = (c0+2==rank)?1.f:0.f;  m0.w = (c0+3==rank)?1.f:0.f;
    m1.x = (c0+4==rank)?1.f:0.f;  m1.y = (c0+5==rank)?1.f:0.f;
    m1.z = (c0+6==rank)?1.f:0.f;  m1.w = (c0+7==rank)?1.f:0.f;
    cc0.x = m0.x*gate; cc0.y = m0.y*gate; cc0.z = m0.z*gate; cc0.w = m0.w*gate;
    cc1.x = m1.x*gate; cc1.y = m1.y*gate; cc1.z = m1.z*gate; cc1.w = m1.w*gate;

    ((float4*)mrow)[c8 * 2 + 0] = m0;
    ((float4*)mrow)[c8 * 2 + 1] = m1;
    float* crow = outb + (size_t)OUT1_ELEMS + row * CAP;
    ((float4*)crow)[c8 * 2 + 0] = cc0;
    ((float4*)crow)[c8 * 2 + 1] = cc1;
}

// ---------------------------------------------------------------------------
extern "C" void kernel_launch(void* const* d_in, const int* in_sizes, int n_in,
                              void* d_out, int out_size, void* d_ws, size_t ws_size,
                              hipStream_t stream) {
    const float* X     = (const float*)d_in[0];   // [4,2048,1024] fp32 (proven)
    const float* W     = (const float*)d_in[1];   // [1024,64]     fp32
    const float* noise = (const float*)d_in[2];   // [4,2048,64]   fp32
    float* outb = (float*)d_out;   // mask [.,64] ++ combine [.,64], fp32

    gates_kernel<<<NTOK / 4, 256, 0, stream>>>(X, W, noise, outb);
    rank_kernel<<<BB * EE, 512, 0, stream>>>(outb, outb);
    writer_kernel<<<(NROW * 8) / 256, 256, 0, stream>>>(outb);
}